// Round 20
// baseline (286.500 us; speedup 1.0000x reference)
//
#include <hip/hip_runtime.h>

typedef __attribute__((ext_vector_type(8))) short bf16x8;
typedef __attribute__((ext_vector_type(4))) float f32x4;
typedef unsigned short u16;
typedef unsigned int u32;

#define NN 8192
#define FD 256

__device__ __forceinline__ u16 f2bf(float f) {
  union { float f; unsigned u; } v; v.f = f;
  unsigned r = v.u + 0x7FFF + ((v.u >> 16) & 1);
  return (u16)(r >> 16);
}

__device__ __forceinline__ bf16x8 ldcvt8(const float* __restrict__ p) {
  f32x4 x0 = *(const f32x4*)p;
  f32x4 x1 = *(const f32x4*)(p + 4);
  bf16x8 t;
  t[0] = (short)f2bf(x0[0]); t[1] = (short)f2bf(x0[1]);
  t[2] = (short)f2bf(x0[2]); t[3] = (short)f2bf(x0[3]);
  t[4] = (short)f2bf(x1[0]); t[5] = (short)f2bf(x1[1]);
  t[6] = (short)f2bf(x1[2]); t[7] = (short)f2bf(x1[3]);
  return t;
}

__device__ __forceinline__ void gl16(const void* g, void* l) {
  __builtin_amdgcn_global_load_lds((const __attribute__((address_space(1))) u32*)g,
                                   (__attribute__((address_space(3))) u32*)l, 16, 0, 0);
}

// ---- K0: zero src + dst (64 KB) ----
__global__ __launch_bounds__(256) void k_zero(float* __restrict__ p) {
  int g = (blockIdx.x * 256 + threadIdx.x) * 4;
  f32x4 z = {0.f, 0.f, 0.f, 0.f};
  *(f32x4*)(p + g) = z;
}

// ---- K1: Wh = h @ W -> whT[c][r] (bf16), fused src/dst dot + atomicAdd ----
__global__ __launch_bounds__(256) void k_wh(const float* __restrict__ h,
                                            const float* __restrict__ W,
                                            const float* __restrict__ a,
                                            u16* __restrict__ whT,
                                            float* __restrict__ src,
                                            float* __restrict__ dst) {
  int tid = threadIdx.x;
  int lane = tid & 63;
  int wv = tid >> 6;
  int r0 = blockIdx.x * 64 + (wv >> 1) * 32;
  int c0 = blockIdx.y * 64 + (wv & 1) * 32;
  int lr = lane & 15;
  int q = lane >> 4;

  f32x4 acc[2][2] = {};
  for (int kk = 0; kk < FD; kk += 32) {
    int kb = kk + q * 8;
    bf16x8 av[2], bv[2];
#pragma unroll
    for (int m = 0; m < 2; m++)
      av[m] = ldcvt8(h + (size_t)(r0 + m * 16 + lr) * FD + kb);
#pragma unroll
    for (int n = 0; n < 2; n++) {
      int col = c0 + n * 16 + lr;
      const float* p = W + (size_t)kb * FD + col;
      bf16x8 t;
#pragma unroll
      for (int e = 0; e < 8; e++) t[e] = (short)f2bf(p[(size_t)e * FD]);
      bv[n] = t;
    }
#pragma unroll
    for (int m = 0; m < 2; m++)
#pragma unroll
      for (int n = 0; n < 2; n++)
        acc[m][n] = __builtin_amdgcn_mfma_f32_16x16x32_bf16(av[m], bv[n], acc[m][n], 0, 0, 0);
  }
#pragma unroll
  for (int m = 0; m < 2; m++)
#pragma unroll
    for (int n = 0; n < 2; n++) {
      int gc = c0 + n * 16 + lr;
      int gr = r0 + m * 16 + q * 4;
      ushort4 st;
      st.x = f2bf(acc[m][n][0]);
      st.y = f2bf(acc[m][n][1]);
      st.z = f2bf(acc[m][n][2]);
      st.w = f2bf(acc[m][n][3]);
      *(ushort4*)(whT + (size_t)gc * NN + gr) = st;
    }
  float aA0 = a[c0 + lr], aA1 = a[c0 + 16 + lr];
  float aB0 = a[256 + c0 + lr], aB1 = a[256 + c0 + 16 + lr];
#pragma unroll
  for (int m = 0; m < 2; m++)
#pragma unroll
    for (int j = 0; j < 4; j++) {
      float s1 = acc[m][0][j] * aA0 + acc[m][1][j] * aA1;
      float s2 = acc[m][0][j] * aB0 + acc[m][1][j] * aB1;
#pragma unroll
      for (int sh = 1; sh < 16; sh <<= 1) {
        s1 += __shfl_xor(s1, sh);
        s2 += __shfl_xor(s2, sh);
      }
      if (lr == 0) {
        int row = r0 + m * 16 + q * 4 + j;
        atomicAdd(&src[row], s1);
        atomicAdd(&dst[row], s2);
      }
    }
}

// ---- K2: P-gen, 1 row/block (8192 blocks), 32 elem/thread, zero atomics.
// 8 adj f32x4 loads in flight per thread (2x the MLP of prior form);
// 64B contiguous stores; block-level reduce -> plain lg[row] store.
__global__ __launch_bounds__(256) void k_pgen(const float* __restrict__ adj,
                                              const float* __restrict__ src,
                                              const float* __restrict__ dst,
                                              u16* __restrict__ P,
                                              float* __restrict__ lg) {
  __shared__ float lred[4];
  const int row = blockIdx.x;
  const int tid = threadIdx.x;
  const int lane = tid & 63;
  const int w = tid >> 6;
  const int j0 = tid * 32;
  const float* ap = adj + (size_t)row * NN + j0;
  const float s = src[row];
  float lsum = 0.f;
  bf16x8 ov[4];
#pragma unroll
  for (int v = 0; v < 8; v++) {
    f32x4 a = *(const f32x4*)(ap + v * 4);
    f32x4 d = *(const f32x4*)(dst + j0 + v * 4);
#pragma unroll
    for (int e = 0; e < 4; e++) {
      float x = s + d[e];
      x = fmaxf(x, 0.2f * x);
      float p = a[e] * __expf(x);
      lsum += p;
      ov[v >> 1][(v & 1) * 4 + e] = (short)f2bf(p);
    }
  }
  u16* pp = P + (size_t)row * NN + j0;
#pragma unroll
  for (int v = 0; v < 4; v++) *(bf16x8*)(pp + v * 8) = ov[v];
#pragma unroll
  for (int sh = 1; sh < 64; sh <<= 1) lsum += __shfl_xor(lsum, sh);
  if (lane == 0) lred[w] = lsum;
  __syncthreads();
  if (tid == 0) lg[row] = (lred[0] + lred[1]) + (lred[2] + lred[3]);
}

// ---- K3: h' = P @ Wh, faithful m97 geometry: 128x128 tile, 256 thr, 32 KB
// LDS -> 4 blocks/CU (the m97 co-residency that overlaps barrier drains).
// Grid 1024 = 64m x 2n x 8ks (K-slice 1024, 16 steps of BK=64). Wave = 64x64
// quadrant, acc 4x4 (~110 VGPR, 4 waves/SIMD). Consecutive bids share the
// (n,ks) B panel -> L2 reuse. Plain-store partials into 8 slices, no atomics.
__global__ __launch_bounds__(256) void k_gemm(const u16* __restrict__ P,
                                              const u16* __restrict__ whT,
                                              float* __restrict__ hpp) {
  __shared__ u16 As[8192];   // [128][64] b16, swizzled
  __shared__ u16 Bs[8192];   // [128][64] b16, swizzled

  const int tid = threadIdx.x;
  const int lane = tid & 63;
  const int w = tid >> 6;
  const int lr = lane & 15;
  const int q = lane >> 4;
  const int wr = w >> 1;
  const int wc = w & 1;
  const int bid = blockIdx.x;
  const int m = bid & 63;
  const int n = (bid >> 6) & 1;
  const int ks = bid >> 7;
  const int i0 = m * 128;
  const int c0 = n * 128;
  const int kb = ks * 1024;

  const int r8 = lane >> 3;
  const int sg = ((lane & 7) ^ (r8 & 7)) * 8;   // inverse-swizzled source slot
  const u16* srcA = P + (size_t)(i0 + w * 32 + r8) * NN + kb + sg;
  const u16* srcB = whT + (size_t)(c0 + w * 32 + r8) * NN + kb + sg;

  f32x4 acc[4][4] = {};

  for (int t = 0; t < 16; t++) {
#pragma unroll
    for (int i = 0; i < 4; i++) {
      gl16(srcA + (size_t)i * 8 * NN + t * 64, &As[w * 2048 + i * 512]);
      gl16(srcB + (size_t)i * 8 * NN + t * 64, &Bs[w * 2048 + i * 512]);
    }
    __syncthreads();   // tiles ready (compiler-inserted vmcnt drain)
#pragma unroll
    for (int kk = 0; kk < 2; kk++) {
      const int sw = ((kk * 4 + q) ^ (lr & 7)) * 8;
      bf16x8 af[4], bfv[4];
#pragma unroll
      for (int rt = 0; rt < 4; rt++)
        af[rt] = *(const bf16x8*)&As[(wr * 64 + rt * 16 + lr) * 64 + sw];
#pragma unroll
      for (int ct = 0; ct < 4; ct++)
        bfv[ct] = *(const bf16x8*)&Bs[(wc * 64 + ct * 16 + lr) * 64 + sw];
#pragma unroll
      for (int rt = 0; rt < 4; rt++)
#pragma unroll
        for (int ct = 0; ct < 4; ct++)
          acc[rt][ct] = __builtin_amdgcn_mfma_f32_16x16x32_bf16(af[rt], bfv[ct], acc[rt][ct], 0, 0, 0);
    }
    __syncthreads();   // reads done before next stage overwrites
  }

  // plain partial stores into slice ks
  float* hs = hpp + (size_t)ks * NN * FD;
#pragma unroll
  for (int rt = 0; rt < 4; rt++)
#pragma unroll
    for (int ct = 0; ct < 4; ct++) {
      int col = c0 + wc * 64 + ct * 16 + lr;
#pragma unroll
      for (int j = 0; j < 4; j++) {
        int row = i0 + wr * 64 + rt * 16 + q * 4 + j;
        hs[(size_t)row * FD + col] = acc[rt][ct][j];
      }
    }
}

// ---- K4: sum 8 partial slices, normalize by row-sum, cast bf16 ----
__global__ __launch_bounds__(256) void k_norm(const float* __restrict__ hpp,
                                              const float* __restrict__ lg,
                                              u16* __restrict__ hpb) {
  int gid = blockIdx.x * 256 + threadIdx.x;
  int idx = gid * 4;
  int row = idx >> 8;
  f32x4 s = {0.f, 0.f, 0.f, 0.f};
#pragma unroll
  for (int sl = 0; sl < 8; sl++)
    s += *(const f32x4*)(hpp + (size_t)sl * NN * FD + idx);
  float inv = 1.0f / lg[row];
  ushort4 st;
  st.x = f2bf(s[0] * inv);
  st.y = f2bf(s[1] * inv);
  st.z = f2bf(s[2] * inv);
  st.w = f2bf(s[3] * inv);
  *(ushort4*)(hpb + idx) = st;
}

// ---- K5: fused GRUCell (h, w_ih, w_hh cast f32->bf16 inline) ----
__global__ __launch_bounds__(256) void k_gru(const u16* __restrict__ hpb,
                                             const float* __restrict__ h,
                                             const float* __restrict__ wih,
                                             const float* __restrict__ whh,
                                             const float* __restrict__ bih,
                                             const float* __restrict__ bhh,
                                             float* __restrict__ out) {
  int tid = threadIdx.x;
  int lane = tid & 63;
  int wv = tid >> 6;
  int i0 = blockIdx.x * 32;
  int lr = lane & 15;
  int q = lane >> 4;
  int c = blockIdx.y * 64 + wv * 16 + lr;
  f32x4 gi[3][2] = {};
  f32x4 gh[3][2] = {};
  for (int kk = 0; kk < FD; kk += 32) {
    int kb = kk + q * 8;
    bf16x8 ap[2], ah[2], bi[3], bh[3];
#pragma unroll
    for (int m = 0; m < 2; m++) {
      ap[m] = *(const bf16x8*)(hpb + (size_t)(i0 + m * 16 + lr) * FD + kb);
      ah[m] = ldcvt8(h + (size_t)(i0 + m * 16 + lr) * FD + kb);
    }
#pragma unroll
    for (int g = 0; g < 3; g++) {
      bi[g] = ldcvt8(wih + (size_t)(g * 256 + c) * FD + kb);
      bh[g] = ldcvt8(whh + (size_t)(g * 256 + c) * FD + kb);
    }
#pragma unroll
    for (int g = 0; g < 3; g++)
#pragma unroll
      for (int m = 0; m < 2; m++) {
        gi[g][m] = __builtin_amdgcn_mfma_f32_16x16x32_bf16(ap[m], bi[g], gi[g][m], 0, 0, 0);
        gh[g][m] = __builtin_amdgcn_mfma_f32_16x16x32_bf16(ah[m], bh[g], gh[g][m], 0, 0, 0);
      }
  }
  float bir = bih[c], biz = bih[256 + c], bin = bih[512 + c];
  float bhr = bhh[c], bhz = bhh[256 + c], bhn = bhh[512 + c];
#pragma unroll
  for (int m = 0; m < 2; m++)
#pragma unroll
    for (int j = 0; j < 4; j++) {
      int row = i0 + m * 16 + q * 4 + j;
      float rv = gi[0][m][j] + bir + gh[0][m][j] + bhr;
      float zv = gi[1][m][j] + biz + gh[1][m][j] + bhz;
      float r = 1.f / (1.f + __expf(-rv));
      float z = 1.f / (1.f + __expf(-zv));
      float nx = gi[2][m][j] + bin + r * (gh[2][m][j] + bhn);
      float n = 1.f - 2.f / (__expf(2.f * nx) + 1.f);
      float hv = h[(size_t)row * FD + c];
      out[(size_t)row * FD + c] = (1.f - z) * n + z * hv;
    }
}

extern "C" void kernel_launch(void* const* d_in, const int* in_sizes, int n_in,
                              void* d_out, int out_size, void* d_ws, size_t ws_size,
                              hipStream_t stream) {
  const float* h   = (const float*)d_in[0];
  const float* adj = (const float*)d_in[1];
  const float* W   = (const float*)d_in[2];
  const float* a   = (const float*)d_in[3];
  const float* wih = (const float*)d_in[4];
  const float* whh = (const float*)d_in[5];
  const float* bih = (const float*)d_in[6];
  const float* bhh = (const float*)d_in[7];
  float* out = (float*)d_out;

  // ws layout (~196 MB; ws ~1 GB per harness poison fill):
  char* ws = (char*)d_ws;
  u16* whT   = (u16*)(ws);                   // [0, 4 MB)  Wh^T bf16; aliased by hpb after k_gemm
  u16* hpb   = (u16*)(ws);                   //   alias
  float* hpp = (float*)(ws + 4194304);       // [4, 68 MB) 8 x h'-partial slices f32
  float* lgv = (float*)(ws + 71303168);      // 32 KB row sums (plain-stored by k_pgen)
  float* srcv = (float*)(ws + 71335936);     // 32 KB
  float* dstv = (float*)(ws + 71368704);     // 32 KB
  u16* P     = (u16*)(ws + 71401472);        // 128 MB P bf16 (8192x8192)
  (void)ws_size;

  k_zero<<<16, 256, 0, stream>>>(srcv);      // src+dst (64 KB contiguous)
  k_wh<<<dim3(128, 4), 256, 0, stream>>>(h, W, a, whT, srcv, dstv);
  k_pgen<<<8192, 256, 0, stream>>>(adj, srcv, dstv, P, lgv);
  k_gemm<<<1024, 256, 0, stream>>>(P, whT, hpp);
  k_norm<<<2048, 256, 0, stream>>>(hpp, lgv, hpb);
  k_gru<<<dim3(256, 4), 256, 0, stream>>>(hpb, h, wih, whh, bih, bhh, out);
}

// Round 21
// 215.635 us; speedup vs baseline: 1.3286x; 1.3286x over previous
//
#include <hip/hip_runtime.h>

typedef __attribute__((ext_vector_type(8))) short bf16x8;
typedef __attribute__((ext_vector_type(4))) float f32x4;
typedef unsigned short u16;
typedef unsigned int u32;

#define NN 8192
#define FD 256

__device__ __forceinline__ u16 f2bf(float f) {
  union { float f; unsigned u; } v; v.f = f;
  unsigned r = v.u + 0x7FFF + ((v.u >> 16) & 1);
  return (u16)(r >> 16);
}

__device__ __forceinline__ bf16x8 ldcvt8(const float* __restrict__ p) {
  f32x4 x0 = *(const f32x4*)p;
  f32x4 x1 = *(const f32x4*)(p + 4);
  bf16x8 t;
  t[0] = (short)f2bf(x0[0]); t[1] = (short)f2bf(x0[1]);
  t[2] = (short)f2bf(x0[2]); t[3] = (short)f2bf(x0[3]);
  t[4] = (short)f2bf(x1[0]); t[5] = (short)f2bf(x1[1]);
  t[6] = (short)f2bf(x1[2]); t[7] = (short)f2bf(x1[3]);
  return t;
}

__device__ __forceinline__ void gl16(const void* g, void* l) {
  __builtin_amdgcn_global_load_lds((const __attribute__((address_space(1))) u32*)g,
                                   (__attribute__((address_space(3))) u32*)l, 16, 0, 0);
}

// ---- K0: zero src + dst (64 KB) ----
__global__ __launch_bounds__(256) void k_zero(float* __restrict__ p) {
  int g = (blockIdx.x * 256 + threadIdx.x) * 4;
  f32x4 z = {0.f, 0.f, 0.f, 0.f};
  *(f32x4*)(p + g) = z;
}

// ---- K1: Wh = h @ W -> whT[c][r] (bf16), fused src/dst dot + atomicAdd ----
__global__ __launch_bounds__(256) void k_wh(const float* __restrict__ h,
                                            const float* __restrict__ W,
                                            const float* __restrict__ a,
                                            u16* __restrict__ whT,
                                            float* __restrict__ src,
                                            float* __restrict__ dst) {
  int tid = threadIdx.x;
  int lane = tid & 63;
  int wv = tid >> 6;
  int r0 = blockIdx.x * 64 + (wv >> 1) * 32;
  int c0 = blockIdx.y * 64 + (wv & 1) * 32;
  int lr = lane & 15;
  int q = lane >> 4;

  f32x4 acc[2][2] = {};
  for (int kk = 0; kk < FD; kk += 32) {
    int kb = kk + q * 8;
    bf16x8 av[2], bv[2];
#pragma unroll
    for (int m = 0; m < 2; m++)
      av[m] = ldcvt8(h + (size_t)(r0 + m * 16 + lr) * FD + kb);
#pragma unroll
    for (int n = 0; n < 2; n++) {
      int col = c0 + n * 16 + lr;
      const float* p = W + (size_t)kb * FD + col;
      bf16x8 t;
#pragma unroll
      for (int e = 0; e < 8; e++) t[e] = (short)f2bf(p[(size_t)e * FD]);
      bv[n] = t;
    }
#pragma unroll
    for (int m = 0; m < 2; m++)
#pragma unroll
      for (int n = 0; n < 2; n++)
        acc[m][n] = __builtin_amdgcn_mfma_f32_16x16x32_bf16(av[m], bv[n], acc[m][n], 0, 0, 0);
  }
#pragma unroll
  for (int m = 0; m < 2; m++)
#pragma unroll
    for (int n = 0; n < 2; n++) {
      int gc = c0 + n * 16 + lr;
      int gr = r0 + m * 16 + q * 4;
      ushort4 st;
      st.x = f2bf(acc[m][n][0]);
      st.y = f2bf(acc[m][n][1]);
      st.z = f2bf(acc[m][n][2]);
      st.w = f2bf(acc[m][n][3]);
      *(ushort4*)(whT + (size_t)gc * NN + gr) = st;
    }
  float aA0 = a[c0 + lr], aA1 = a[c0 + 16 + lr];
  float aB0 = a[256 + c0 + lr], aB1 = a[256 + c0 + 16 + lr];
#pragma unroll
  for (int m = 0; m < 2; m++)
#pragma unroll
    for (int j = 0; j < 4; j++) {
      float s1 = acc[m][0][j] * aA0 + acc[m][1][j] * aA1;
      float s2 = acc[m][0][j] * aB0 + acc[m][1][j] * aB1;
#pragma unroll
      for (int sh = 1; sh < 16; sh <<= 1) {
        s1 += __shfl_xor(s1, sh);
        s2 += __shfl_xor(s2, sh);
      }
      if (lr == 0) {
        int row = r0 + m * 16 + q * 4 + j;
        atomicAdd(&src[row], s1);
        atomicAdd(&dst[row], s2);
      }
    }
}

// ---- K2: FUSED P-gen + m97-structure GEMM. Grid 512 = 64m x 8ks, 512 thr
// (8 waves), 2 blocks/CU via __launch_bounds__(512,4) (128-VGPR cap).
// Block: 128 rows x 256 cols (full N -> each P consumed ONCE, adj read once,
// P never materialized). K-slice 1024, 16 steps of BK=64.
// Per step: B tile (256x64, 32KB) via inverse-swizzled gl16 (R19-proven);
// A tile = P computed in regs from adj (prefetched 1 step ahead) -> ds_write
// into matching-swizzle As; 2 barriers; wave = 64x64, acc 4x4, 32 MFMA.
// Row-sum partials + C partials plain-stored per ks slice (no atomics).
__global__ __launch_bounds__(512, 4) void k_gatt(const float* __restrict__ adj,
                                                 const u16* __restrict__ whT,
                                                 const float* __restrict__ src,
                                                 const float* __restrict__ dst,
                                                 float* __restrict__ hpp,
                                                 float* __restrict__ lgp) {
  __shared__ u16 As[8192];        // [128 r][64 k] bf16, swizzled
  __shared__ u16 Bs[16384];       // [256 c][64 k] bf16, swizzled
  __shared__ float dst_lds[1024]; // dst k-slice

  const int tid = threadIdx.x;
  const int lane = tid & 63;
  const int w = tid >> 6;
  const int lr = lane & 15;
  const int q = lane >> 4;
  const int wr = w >> 2;          // 64-row half
  const int wc = w & 3;           // 64-col quarter
  const int bid = blockIdx.x;
  const int m = bid & 63;
  const int ks = bid >> 6;
  const int i0 = m * 128;
  const int kb = ks * 1024;

  // P-gen: thread -> row pr (0..127), k-slots ts and ts+4 (k = ts*8, ts*8+32)
  const int pr = tid >> 2;
  const int ts = tid & 3;
  const float* ap = adj + (size_t)(i0 + pr) * NN + kb + ts * 8;
  const float sv = src[i0 + pr];
  const int aw0 = pr * 64 + ((ts ^ (pr & 7)) * 8);
  const int aw1 = pr * 64 + (((ts + 4) ^ (pr & 7)) * 8);

  // B staging: wave w stages cols [w*32, w*32+32), 4 gl16
  const int r8 = lane >> 3;
  const int sgB = ((lane & 7) ^ (r8 & 7)) * 8;
  const u16* srcB = whT + (size_t)(w * 32 + r8) * NN + kb + sgB;

  f32x4 acc[4][4] = {};
  float lsum = 0.f;
  f32x4 ar0, ar1, ar2, ar3;       // 16 adj values (current step)

#define ALD(T)                                                               \
  { ar0 = *(const f32x4*)(ap + (size_t)(T) * 64);                            \
    ar1 = *(const f32x4*)(ap + (size_t)(T) * 64 + 4);                        \
    ar2 = *(const f32x4*)(ap + (size_t)(T) * 64 + 32);                       \
    ar3 = *(const f32x4*)(ap + (size_t)(T) * 64 + 36); }
#define PGEN(T)                                                              \
  {                                                                          \
    f32x4 d0 = *(const f32x4*)&dst_lds[(T) * 64 + ts * 8];                   \
    f32x4 d1 = *(const f32x4*)&dst_lds[(T) * 64 + ts * 8 + 4];               \
    f32x4 d2 = *(const f32x4*)&dst_lds[(T) * 64 + ts * 8 + 32];              \
    f32x4 d3 = *(const f32x4*)&dst_lds[(T) * 64 + ts * 8 + 36];              \
    bf16x8 o0, o1;                                                           \
    _Pragma("unroll") for (int e = 0; e < 4; e++) {                          \
      float x = sv + d0[e]; x = fmaxf(x, 0.2f * x);                          \
      float p = ar0[e] * __expf(x); lsum += p; o0[e] = (short)f2bf(p);       \
    }                                                                        \
    _Pragma("unroll") for (int e = 0; e < 4; e++) {                          \
      float x = sv + d1[e]; x = fmaxf(x, 0.2f * x);                          \
      float p = ar1[e] * __expf(x); lsum += p; o0[4 + e] = (short)f2bf(p);   \
    }                                                                        \
    _Pragma("unroll") for (int e = 0; e < 4; e++) {                          \
      float x = sv + d2[e]; x = fmaxf(x, 0.2f * x);                          \
      float p = ar2[e] * __expf(x); lsum += p; o1[e] = (short)f2bf(p);       \
    }                                                                        \
    _Pragma("unroll") for (int e = 0; e < 4; e++) {                          \
      float x = sv + d3[e]; x = fmaxf(x, 0.2f * x);                          \
      float p = ar3[e] * __expf(x); lsum += p; o1[4 + e] = (short)f2bf(p);   \
    }                                                                        \
    *(bf16x8*)&As[aw0] = o0;                                                 \
    *(bf16x8*)&As[aw1] = o1;                                                 \
  }

  // prologue: dst slice to LDS, first adj
  if (tid < 256) {
    f32x4 v = *(const f32x4*)(dst + kb + tid * 4);
    *(f32x4*)&dst_lds[tid * 4] = v;
  }
  ALD(0);
  __syncthreads();                // dst_lds visible

  for (int t = 0; t < 16; t++) {
#pragma unroll
    for (int i = 0; i < 4; i++)
      gl16(srcB + (size_t)i * 8 * NN + t * 64, &Bs[w * 2048 + i * 512]);
    PGEN(t);
    __syncthreads();              // drains gl16 (vmcnt) + ds_write (lgkm)
    if (t + 1 < 16) ALD(t + 1);   // prefetch next adj under MFMA phase
#pragma unroll
    for (int kk = 0; kk < 2; kk++) {
      const int sw = ((kk * 4 + q) ^ (lr & 7)) * 8;
      bf16x8 af[4], bfv[4];
#pragma unroll
      for (int rt = 0; rt < 4; rt++)
        af[rt] = *(const bf16x8*)&As[(wr * 64 + rt * 16 + lr) * 64 + sw];
#pragma unroll
      for (int ct = 0; ct < 4; ct++)
        bfv[ct] = *(const bf16x8*)&Bs[(wc * 64 + ct * 16 + lr) * 64 + sw];
#pragma unroll
      for (int rt = 0; rt < 4; rt++)
#pragma unroll
        for (int ct = 0; ct < 4; ct++)
          acc[rt][ct] = __builtin_amdgcn_mfma_f32_16x16x32_bf16(af[rt], bfv[ct], acc[rt][ct], 0, 0, 0);
    }
    __syncthreads();              // reads done before next stage overwrites
  }
#undef ALD
#undef PGEN

  // row-sum partial for this ks slice: 4 threads per row
  lsum += __shfl_xor(lsum, 1);
  lsum += __shfl_xor(lsum, 2);
  if ((lane & 3) == 0) lgp[ks * NN + i0 + pr] = lsum;

  // C partial plain stores into slice ks
  float* hs = hpp + (size_t)ks * NN * FD;
#pragma unroll
  for (int rt = 0; rt < 4; rt++)
#pragma unroll
    for (int ct = 0; ct < 4; ct++) {
      int col = wc * 64 + ct * 16 + lr;
#pragma unroll
      for (int j = 0; j < 4; j++) {
        int row = i0 + wr * 64 + rt * 16 + q * 4 + j;
        hs[(size_t)row * FD + col] = acc[rt][ct][j];
      }
    }
}

// ---- K3: sum 8 partial slices (hp and lg), normalize, cast bf16 ----
__global__ __launch_bounds__(256) void k_norm(const float* __restrict__ hpp,
                                              const float* __restrict__ lgp,
                                              u16* __restrict__ hpb) {
  int gid = blockIdx.x * 256 + threadIdx.x;
  int idx = gid * 4;
  int row = idx >> 8;
  f32x4 s = {0.f, 0.f, 0.f, 0.f};
  float l = 0.f;
#pragma unroll
  for (int sl = 0; sl < 8; sl++) {
    s += *(const f32x4*)(hpp + (size_t)sl * NN * FD + idx);
    l += lgp[sl * NN + row];
  }
  float inv = 1.0f / l;
  ushort4 st;
  st.x = f2bf(s[0] * inv);
  st.y = f2bf(s[1] * inv);
  st.z = f2bf(s[2] * inv);
  st.w = f2bf(s[3] * inv);
  *(ushort4*)(hpb + idx) = st;
}

// ---- K4: fused GRUCell (h, w_ih, w_hh cast f32->bf16 inline) ----
__global__ __launch_bounds__(256) void k_gru(const u16* __restrict__ hpb,
                                             const float* __restrict__ h,
                                             const float* __restrict__ wih,
                                             const float* __restrict__ whh,
                                             const float* __restrict__ bih,
                                             const float* __restrict__ bhh,
                                             float* __restrict__ out) {
  int tid = threadIdx.x;
  int lane = tid & 63;
  int wv = tid >> 6;
  int i0 = blockIdx.x * 32;
  int lr = lane & 15;
  int q = lane >> 4;
  int c = blockIdx.y * 64 + wv * 16 + lr;
  f32x4 gi[3][2] = {};
  f32x4 gh[3][2] = {};
  for (int kk = 0; kk < FD; kk += 32) {
    int kb = kk + q * 8;
    bf16x8 ap[2], ah[2], bi[3], bh[3];
#pragma unroll
    for (int m = 0; m < 2; m++) {
      ap[m] = *(const bf16x8*)(hpb + (size_t)(i0 + m * 16 + lr) * FD + kb);
      ah[m] = ldcvt8(h + (size_t)(i0 + m * 16 + lr) * FD + kb);
    }
#pragma unroll
    for (int g = 0; g < 3; g++) {
      bi[g] = ldcvt8(wih + (size_t)(g * 256 + c) * FD + kb);
      bh[g] = ldcvt8(whh + (size_t)(g * 256 + c) * FD + kb);
    }
#pragma unroll
    for (int g = 0; g < 3; g++)
#pragma unroll
      for (int m = 0; m < 2; m++) {
        gi[g][m] = __builtin_amdgcn_mfma_f32_16x16x32_bf16(ap[m], bi[g], gi[g][m], 0, 0, 0);
        gh[g][m] = __builtin_amdgcn_mfma_f32_16x16x32_bf16(ah[m], bh[g], gh[g][m], 0, 0, 0);
      }
  }
  float bir = bih[c], biz = bih[256 + c], bin = bih[512 + c];
  float bhr = bhh[c], bhz = bhh[256 + c], bhn = bhh[512 + c];
#pragma unroll
  for (int m = 0; m < 2; m++)
#pragma unroll
    for (int j = 0; j < 4; j++) {
      int row = i0 + m * 16 + q * 4 + j;
      float rv = gi[0][m][j] + bir + gh[0][m][j] + bhr;
      float zv = gi[1][m][j] + biz + gh[1][m][j] + bhz;
      float r = 1.f / (1.f + __expf(-rv));
      float z = 1.f / (1.f + __expf(-zv));
      float nx = gi[2][m][j] + bin + r * (gh[2][m][j] + bhn);
      float n = 1.f - 2.f / (__expf(2.f * nx) + 1.f);
      float hv = h[(size_t)row * FD + c];
      out[(size_t)row * FD + c] = (1.f - z) * n + z * hv;
    }
}

extern "C" void kernel_launch(void* const* d_in, const int* in_sizes, int n_in,
                              void* d_out, int out_size, void* d_ws, size_t ws_size,
                              hipStream_t stream) {
  const float* h   = (const float*)d_in[0];
  const float* adj = (const float*)d_in[1];
  const float* W   = (const float*)d_in[2];
  const float* a   = (const float*)d_in[3];
  const float* wih = (const float*)d_in[4];
  const float* whh = (const float*)d_in[5];
  const float* bih = (const float*)d_in[6];
  const float* bhh = (const float*)d_in[7];
  float* out = (float*)d_out;

  // ws layout (~68.5 MB; ws ~1 GB per harness poison fill):
  char* ws = (char*)d_ws;
  u16* whT   = (u16*)(ws);                   // [0, 4 MB)  Wh^T bf16; aliased by hpb after k_gatt
  u16* hpb   = (u16*)(ws);                   //   alias
  float* hpp = (float*)(ws + 4194304);       // [4, 68 MB) 8 x h'-partial slices f32
  float* lgp = (float*)(ws + 71303168);      // 256 KB row-sum partial slices
  float* srcv = (float*)(ws + 71565312);     // 32 KB
  float* dstv = (float*)(ws + 71598080);     // 32 KB
  (void)ws_size;

  k_zero<<<16, 256, 0, stream>>>(srcv);      // src+dst (64 KB contiguous)
  k_wh<<<dim3(128, 4), 256, 0, stream>>>(h, W, a, whT, srcv, dstv);
  k_gatt<<<512, 512, 0, stream>>>(adj, whT, srcv, dstv, hpp, lgp);
  k_norm<<<2048, 256, 0, stream>>>(hpp, lgp, hpb);
  k_gru<<<dim3(256, 4), 256, 0, stream>>>(hpb, h, wih, whh, bih, bhh, out);
}